// Round 6
// baseline (500.777 us; speedup 1.0000x reference)
//
#include <hip/hip_runtime.h>
#include <hip/hip_bf16.h>
#include <math.h>

#define NNODES 50000
#define NEDGES 800000
#define HNB 128                 // histogram blocks per row
#define HBINS 50176             // 196*256, >= NNODES
#define SCAN_NB 196             // HBINS/256

typedef short s8v __attribute__((ext_vector_type(8)));
typedef float f4v __attribute__((ext_vector_type(4)));
typedef unsigned int u32;
using bf16 = __hip_bfloat16;

static __device__ __forceinline__ float bflo(unsigned int x) {
    union { unsigned int i; float f; } c; c.i = x << 16; return c.f;
}
static __device__ __forceinline__ float bfhi(unsigned int x) {
    union { unsigned int i; float f; } c; c.i = x & 0xffff0000u; return c.f;
}
// async global->LDS, 16 B per lane; LDS dst = wave-uniform base + lane*16
static __device__ __forceinline__ void gld_lds16(const void* g, void* l) {
    __builtin_amdgcn_global_load_lds((const __attribute__((address_space(1))) u32*)g,
                                     (__attribute__((address_space(3))) u32*)l, 16, 0, 0);
}

// ---------------- weight prep: pack transposed [W | LW]^T -> bf16 wcatT[C2][K] ----------------

__global__ void k_packbt(const float* __restrict__ W, const float* __restrict__ LW,
                         bf16* __restrict__ out, int K, int C) {
    int i = blockIdx.x * blockDim.x + threadIdx.x;
    int C2 = 2 * C;
    if (i >= K * C2) return;
    int n = i / K, k = i % K;   // out[n][k] = B[k][n]
    float v = (n < C) ? W[k * C + n] : LW[k * C + (n - C)];
    out[i] = __float2bfloat16(v);
}

// ---------------- degree histograms via LDS (no global atomics) ----------------

__global__ __launch_bounds__(256) void k_hist(const int* __restrict__ ei, ushort* __restrict__ partials) {
    __shared__ unsigned int h32[HBINS / 2];   // 100352 B LDS
    int b = blockIdx.x, row = blockIdx.y, t = threadIdx.x;
    for (int i = t; i < HBINS / 2; i += 256) h32[i] = 0;
    __syncthreads();
    const int chunk = NEDGES / HNB;  // 6250
    int beg = b * chunk, end = beg + chunk;
    const int* p = ei + (size_t)row * NEDGES;
    for (int e = beg + t; e < end; e += 256) {
        int id = p[e];
        atomicAdd(&h32[id >> 1], 1u << (16 * (id & 1)));
    }
    __syncthreads();
    unsigned int* o32 = (unsigned int*)(partials + ((size_t)row * HNB + b) * HBINS);
    for (int i = t; i < HBINS / 2; i += 256) o32[i] = h32[i];
}

// reduce partials: y=0 -> rsqrt_out table; y=1 -> in_cnt + per-256-node block_sums
__global__ __launch_bounds__(256) void k_hist_reduce(const ushort* __restrict__ partials,
                                                     float* __restrict__ rsqrt_out,
                                                     int* __restrict__ in_cnt,
                                                     int* __restrict__ block_sums) {
    __shared__ int sm[256];
    int row = blockIdx.y;
    int i = blockIdx.x * 256 + threadIdx.x;
    const ushort* p = partials + (size_t)row * HNB * HBINS + i;
    int s = 0;
#pragma unroll 4
    for (int b = 0; b < HNB; ++b) s += p[(size_t)b * HBINS];
    if (row == 0) {
        if (i < NNODES) rsqrt_out[i] = rsqrtf((float)s);
    } else {
        if (i < NNODES) in_cnt[i] = s;
        sm[threadIdx.x] = s;
        __syncthreads();
        for (int off = 128; off > 0; off >>= 1) {
            if (threadIdx.x < off) sm[threadIdx.x] += sm[threadIdx.x + off];
            __syncthreads();
        }
        if (threadIdx.x == 0) block_sums[blockIdx.x] = sm[0];
    }
}

// ---------------- scan ----------------

__global__ void k_scan_blocks(const int* __restrict__ block_sums, int* __restrict__ block_base, int nb) {
    __shared__ int s[256];
    int t = threadIdx.x;
    int v = (t < nb) ? block_sums[t] : 0;
    s[t] = v;
    __syncthreads();
    for (int off = 1; off < 256; off <<= 1) {
        int u = (t >= off) ? s[t - off] : 0;
        __syncthreads();
        s[t] += u;
        __syncthreads();
    }
    block_base[t] = s[t] - v;  // exclusive
}

__global__ void k_scan_final(const int* __restrict__ in_cnt, const int* __restrict__ block_base,
                             int* __restrict__ offsets, int* __restrict__ cursor) {
    __shared__ int s[256];
    int b = blockIdx.x, t = threadIdx.x;
    int i = b * 256 + t;
    int v = (i < NNODES) ? in_cnt[i] : 0;
    s[t] = v;
    __syncthreads();
    for (int off = 1; off < 256; off <<= 1) {
        int u = (t >= off) ? s[t - off] : 0;
        __syncthreads();
        s[t] += u;
        __syncthreads();
    }
    int excl = s[t] - v + block_base[b];
    if (i < NNODES) { offsets[i] = excl; cursor[i] = excl; }
    if (i == NNODES - 1) offsets[NNODES] = excl + v;
}

// counting-sort scatter: src id only
__global__ void k_scatter(const int* __restrict__ ei, int* __restrict__ cursor,
                          int* __restrict__ src_sorted) {
    int e = blockIdx.x * blockDim.x + threadIdx.x;
    if (e < NEDGES) {
        int r = ei[e], c = ei[NEDGES + e];
        int p = atomicAdd(&cursor[c], 1);
        src_sorted[p] = r;
    }
}

// ---------------- fused aggregate: column-split passes for L2 locality ----------------
// grid (ceil(N/4), P): 4 nodes/block (1 wave each), pass y covers cols [y*64, y*64+64).
// Per-pass unique gather footprint = N*128 B = 6.4 MB (vs 51 MB unsplit) -> L2-resident.
// 8 lanes per edge-chunk (16 B/lane), 8 edges in parallel, unroll x2.
// ACT: 1 = relu -> bf16, 2 = sigmoid -> fp32.
template<int D, int C2, int ACT>
__global__ __launch_bounds__(256) void k_agg_fused(const bf16* __restrict__ xwcat,
                                                   const int* __restrict__ offsets,
                                                   const int* __restrict__ src_sorted,
                                                   const float* __restrict__ rsqrt_out,
                                                   const float* __restrict__ bias,
                                                   void* __restrict__ out) {
    const int U = 2;
    int lane = threadIdx.x & 63;
    int v = blockIdx.x * 4 + (threadIdx.x >> 6);
    if (v >= NNODES) return;
    int col0 = blockIdx.y * 64;
    int g = lane >> 3, sl = lane & 7;

    int beg = offsets[v], end = offsets[v + 1];
    int deg = end - beg;
    int dcap = min(deg, 64);

    // preload bucket ids + out-norms (lanes >= dcap: id=0, w=0 -> harmless)
    int id = 0; float wl = 0.f;
    if (lane < dcap) {
        id = src_sorted[beg + lane];
        wl = rsqrt_out[id];
    }

    float acc[U][8];
#pragma unroll
    for (int u = 0; u < U; ++u)
#pragma unroll
        for (int c = 0; c < 8; ++c) acc[u][c] = 0.f;

    const ushort* base = (const ushort*)xwcat + col0 + sl * 8;

    for (int e0 = 0; e0 < dcap; e0 += 8 * U) {
#pragma unroll
        for (int u = 0; u < U; ++u) {
            int e = e0 + u * 8 + g;
            int s = __shfl(id, e & 63, 64);
            float w = __shfl(wl, e & 63, 64);
            if (e >= dcap) w = 0.f;
            uint4 q = *(const uint4*)(base + (size_t)s * C2);
            acc[u][0] += w * bflo(q.x); acc[u][1] += w * bfhi(q.x);
            acc[u][2] += w * bflo(q.y); acc[u][3] += w * bfhi(q.y);
            acc[u][4] += w * bflo(q.z); acc[u][5] += w * bfhi(q.z);
            acc[u][6] += w * bflo(q.w); acc[u][7] += w * bfhi(q.w);
        }
    }
    // rare tail: deg > 64
    for (int j = beg + 64 + g; j < end; j += 8) {
        int s = src_sorted[j];
        float w = rsqrt_out[s];
        uint4 q = *(const uint4*)(base + (size_t)s * C2);
        acc[0][0] += w * bflo(q.x); acc[0][1] += w * bfhi(q.x);
        acc[0][2] += w * bflo(q.y); acc[0][3] += w * bfhi(q.y);
        acc[0][4] += w * bflo(q.z); acc[0][5] += w * bfhi(q.z);
        acc[0][6] += w * bflo(q.w); acc[0][7] += w * bfhi(q.w);
    }

#pragma unroll
    for (int c = 0; c < 8; ++c) acc[0][c] += acc[1][c];
    // reduce across the 8 groups: lanes [0,8) end with full sums
#pragma unroll
    for (int d = 32; d >= 8; d >>= 1) {
#pragma unroll
        for (int c = 0; c < 8; ++c) acc[0][c] += __shfl_down(acc[0][c], d, 64);
    }

    if (lane < 8) {
        float sc = (deg > 0) ? rsqrtf((float)deg) : 0.f;
        const ushort* lwp = (const ushort*)xwcat + (size_t)v * C2 + D + col0 + sl * 8;
        uint4 ql = *(const uint4*)lwp;
        const float* bp = bias + col0 + sl * 8;
        float4 b0 = *(const float4*)bp, b1 = *(const float4*)(bp + 4);
        float h[8];
        h[0] = acc[0][0] * sc + bflo(ql.x) + b0.x;
        h[1] = acc[0][1] * sc + bfhi(ql.x) + b0.y;
        h[2] = acc[0][2] * sc + bflo(ql.y) + b0.z;
        h[3] = acc[0][3] * sc + bfhi(ql.y) + b0.w;
        h[4] = acc[0][4] * sc + bflo(ql.z) + b1.x;
        h[5] = acc[0][5] * sc + bfhi(ql.z) + b1.y;
        h[6] = acc[0][6] * sc + bflo(ql.w) + b1.z;
        h[7] = acc[0][7] * sc + bfhi(ql.w) + b1.w;
        if (ACT == 1) {
            union { bf16 hh[8]; uint4 u; } o;
#pragma unroll
            for (int c = 0; c < 8; ++c) o.hh[c] = __float2bfloat16(fmaxf(h[c], 0.f));
            *(uint4*)((ushort*)out + (size_t)v * D + col0 + sl * 8) = o.u;
        } else {
            float r[8];
#pragma unroll
            for (int c = 0; c < 8; ++c) r[c] = 1.f / (1.f + expf(-h[c]));
            float* op = (float*)out + (size_t)v * D + col0 + sl * 8;
            *(float4*)op = (float4){r[0], r[1], r[2], r[3]};
            *(float4*)(op + 4) = (float4){r[4], r[5], r[6], r[7]};
        }
    }
}

// ---------------- MFMA GEMM, m97-style: A[N,256] @ BcatT^T -> bf16 xwcat ----------------
// 128x128 tile, BK=32, global_load_lds 16B staging (bf16 A), 4 waves in 2x2,
// 16 MFMA per wave per k-step. Bt is pre-transposed [C2][256].
template<int C2, bool A_BF16>
__global__ __launch_bounds__(256) void k_gemm_fused(const void* __restrict__ Aptr,
                                                    const bf16* __restrict__ Bt,
                                                    bf16* __restrict__ Out) {
    __shared__ bf16 As[128 * 32];   // 8 KB, rows x k, 64 B/row, unpadded (lds-dma layout)
    __shared__ bf16 Bs[128 * 32];   // 8 KB, cols x k
    int t = threadIdx.x;
    int wave = t >> 6, lane = t & 63;
    int r0 = blockIdx.x * 128;
    int n0 = blockIdx.y * 128;
    int wr = wave >> 1, wc = wave & 1;

    f4v acc[4][4];
#pragma unroll
    for (int i = 0; i < 4; ++i)
#pragma unroll
        for (int j = 0; j < 4; ++j) acc[i][j] = (f4v){0.f, 0.f, 0.f, 0.f};

    for (int k0 = 0; k0 < 256; k0 += 32) {
        // ---- stage A tile ----
        if (A_BF16) {
            const char* Ab = (const char*)Aptr;
#pragma unroll
            for (int r = 0; r < 2; ++r) {
                int o = r * 4096 + wave * 1024 + lane * 16;  // byte offset in tile
                int row = o >> 6, kb = o & 63;
                if (r0 + row < NNODES)
                    gld_lds16(Ab + (size_t)(r0 + row) * 512 + k0 * 2 + kb, (char*)As + o);
            }
        } else {
            const float* Af = (const float*)Aptr;
#pragma unroll
            for (int r = 0; r < 2; ++r) {
                int o = r * 4096 + t * 16;                   // byte offset in tile
                int row = o >> 6, kb = o & 63;
                union { bf16 h[8]; uint4 v; } u;
                if (r0 + row < NNODES) {
                    const float4* p = (const float4*)(Af + (size_t)(r0 + row) * 256 + k0 + kb / 2);
                    float4 f0 = p[0], f1 = p[1];
                    u.h[0] = __float2bfloat16(f0.x); u.h[1] = __float2bfloat16(f0.y);
                    u.h[2] = __float2bfloat16(f0.z); u.h[3] = __float2bfloat16(f0.w);
                    u.h[4] = __float2bfloat16(f1.x); u.h[5] = __float2bfloat16(f1.y);
                    u.h[6] = __float2bfloat16(f1.z); u.h[7] = __float2bfloat16(f1.w);
                } else {
                    u.v = (uint4){0, 0, 0, 0};
                }
                *(uint4*)((char*)As + o) = u.v;
            }
        }
        // ---- stage B tile (always bf16, full cols) ----
        {
#pragma unroll
            for (int r = 0; r < 2; ++r) {
                int o = r * 4096 + wave * 1024 + lane * 16;
                int row = o >> 6, kb = o & 63;
                gld_lds16((const char*)Bt + (size_t)(n0 + row) * 512 + k0 * 2 + kb, (char*)Bs + o);
            }
        }
        __syncthreads();
        int ml = lane & 15, kq = (lane >> 4) * 8;
        s8v a[4], b[4];
#pragma unroll
        for (int i = 0; i < 4; ++i)
            a[i] = *(const s8v*)&As[(wr * 64 + i * 16 + ml) * 32 + kq];
#pragma unroll
        for (int j = 0; j < 4; ++j)
            b[j] = *(const s8v*)&Bs[(wc * 64 + j * 16 + ml) * 32 + kq];
#pragma unroll
        for (int i = 0; i < 4; ++i)
#pragma unroll
            for (int j = 0; j < 4; ++j)
                acc[i][j] = __builtin_amdgcn_mfma_f32_16x16x32_bf16(a[i], b[j], acc[i][j], 0, 0, 0);
        __syncthreads();
    }
    // epilogue: C/D layout col=lane&15, row=(lane>>4)*4+reg
    int ml = lane & 15, q4 = (lane >> 4) * 4;
#pragma unroll
    for (int i = 0; i < 4; ++i) {
#pragma unroll
        for (int rr = 0; rr < 4; ++rr) {
            int grow = r0 + wr * 64 + i * 16 + q4 + rr;
            if (grow < NNODES) {
#pragma unroll
                for (int j = 0; j < 4; ++j) {
                    int gcol = n0 + wc * 64 + j * 16 + ml;
                    Out[(size_t)grow * C2 + gcol] = __float2bfloat16(acc[i][j][rr]);
                }
            }
        }
    }
}

// ---------------- launcher ----------------

extern "C" void kernel_launch(void* const* d_in, const int* in_sizes, int n_in,
                              void* d_out, int out_size, void* d_ws, size_t ws_size,
                              hipStream_t stream) {
    const float* x   = (const float*)d_in[0];
    const int*   ei  = (const int*)d_in[1];
    const float* w1  = (const float*)d_in[3];
    const float* lw1 = (const float*)d_in[4];
    const float* lb1 = (const float*)d_in[5];
    const float* w2  = (const float*)d_in[6];
    const float* lw2 = (const float*)d_in[7];
    const float* lb2 = (const float*)d_in[8];
    const float* w3  = (const float*)d_in[9];
    const float* lw3 = (const float*)d_in[10];
    const float* lb3 = (const float*)d_in[11];
    float* out = (float*)d_out;

    char* ws = (char*)d_ws;
    size_t off = 0;
    auto alloc = [&](size_t bytes) -> void* {
        void* p = ws + off;
        off += (bytes + 255) & ~(size_t)255;
        return p;
    };
    int*    in_cnt     = (int*)alloc((size_t)HBINS * 4);
    float*  rsqrt_out  = (float*)alloc((size_t)HBINS * 4);
    int*    offsets    = (int*)alloc((size_t)(NNODES + 1) * 4);
    int*    cursor     = (int*)alloc((size_t)NNODES * 4);
    int*    block_sums = (int*)alloc((size_t)256 * 4);
    int*    block_base = (int*)alloc((size_t)256 * 4);
    ushort* partials   = (ushort*)alloc((size_t)2 * HNB * HBINS * 2);
    int*    src_sorted = (int*)alloc((size_t)NEDGES * 4);
    bf16*   wcat1      = (bf16*)alloc((size_t)512 * 256 * 2);
    bf16*   wcat2      = (bf16*)alloc((size_t)512 * 256 * 2);
    bf16*   wcat3      = (bf16*)alloc((size_t)256 * 256 * 2);
    bf16*   xwcat      = (bf16*)alloc((size_t)NNODES * 512 * 2);
    bf16*   h1         = (bf16*)alloc((size_t)NNODES * 256 * 2);
    bf16*   h2         = (bf16*)alloc((size_t)NNODES * 256 * 2);

    // pack weights -> bf16 transposed [W | LW]^T  ([C2][K])
    k_packbt<<<512, 256, 0, stream>>>(w1, lw1, wcat1, 256, 256);
    k_packbt<<<512, 256, 0, stream>>>(w2, lw2, wcat2, 256, 256);
    k_packbt<<<256, 256, 0, stream>>>(w3, lw3, wcat3, 256, 128);

    // graph preprocessing: LDS histograms -> reduce -> scan -> scatter
    k_hist<<<dim3(HNB, 2), 256, 0, stream>>>(ei, partials);
    k_hist_reduce<<<dim3(SCAN_NB, 2), 256, 0, stream>>>(partials, rsqrt_out, in_cnt, block_sums);
    k_scan_blocks<<<1, 256, 0, stream>>>(block_sums, block_base, SCAN_NB);
    k_scan_final<<<SCAN_NB, 256, 0, stream>>>(in_cnt, block_base, offsets, cursor);
    int eblocks = (NEDGES + 255) / 256;
    k_scatter<<<eblocks, 256, 0, stream>>>(ei, cursor, src_sorted);

    int gx = (NNODES + 127) / 128;   // 391
    int ax = (NNODES + 3) / 4;       // 12500

    // layer 1 (A = x fp32, manual staging)
    k_gemm_fused<512, false><<<dim3(gx, 4), 256, 0, stream>>>(x, wcat1, xwcat);
    k_agg_fused<256, 512, 1><<<dim3(ax, 4), 256, 0, stream>>>(xwcat, offsets, src_sorted, rsqrt_out, lb1, h1);
    // layer 2
    k_gemm_fused<512, true><<<dim3(gx, 4), 256, 0, stream>>>(h1, wcat2, xwcat);
    k_agg_fused<256, 512, 1><<<dim3(ax, 4), 256, 0, stream>>>(xwcat, offsets, src_sorted, rsqrt_out, lb2, h2);
    // layer 3
    k_gemm_fused<256, true><<<dim3(gx, 2), 256, 0, stream>>>(h2, wcat3, xwcat);
    k_agg_fused<128, 256, 2><<<dim3(ax, 2), 256, 0, stream>>>(xwcat, offsets, src_sorted, rsqrt_out, lb3, out);
}

// Round 8
// 466.151 us; speedup vs baseline: 1.0743x; 1.0743x over previous
//
#include <hip/hip_runtime.h>
#include <hip/hip_bf16.h>
#include <math.h>

#define NNODES 50000
#define NEDGES 800000
#define HNB 128                 // histogram blocks per row
#define HBINS 50176             // 196*256, >= NNODES
#define SCAN_NB 196             // HBINS/256

typedef short s8v __attribute__((ext_vector_type(8)));
typedef float f4v __attribute__((ext_vector_type(4)));
typedef unsigned int u32;
using bf16 = __hip_bfloat16;

static __device__ __forceinline__ float bflo(unsigned int x) {
    union { unsigned int i; float f; } c; c.i = x << 16; return c.f;
}
static __device__ __forceinline__ float bfhi(unsigned int x) {
    union { unsigned int i; float f; } c; c.i = x & 0xffff0000u; return c.f;
}
static __device__ __forceinline__ void fma8(float* a, float w, uint4 q) {
    a[0] += w * bflo(q.x); a[1] += w * bfhi(q.x);
    a[2] += w * bflo(q.y); a[3] += w * bfhi(q.y);
    a[4] += w * bflo(q.z); a[5] += w * bfhi(q.z);
    a[6] += w * bflo(q.w); a[7] += w * bfhi(q.w);
}
// async global->LDS, 16 B per lane; LDS dst = wave-uniform base + lane*16
static __device__ __forceinline__ void gld_lds16(const void* g, void* l) {
    __builtin_amdgcn_global_load_lds((const __attribute__((address_space(1))) u32*)g,
                                     (__attribute__((address_space(3))) u32*)l, 16, 0, 0);
}

// ---------------- weight prep: stack+transpose [[W],[LW]] -> bf16 wt[CC][512] ----------------

__global__ void k_packbt(const float* __restrict__ W, const float* __restrict__ LW,
                         bf16* __restrict__ out, int CC) {
    int i = blockIdx.x * blockDim.x + threadIdx.x;
    if (i >= CC * 512) return;
    int n = i / 512, k = i % 512;   // out[n][k] = stackedB[k][n]
    float v = (k < 256) ? W[k * CC + n] : LW[(k - 256) * CC + n];
    out[i] = __float2bfloat16(v);
}

// ---------------- x fp32 -> bf16 into right half of ghcat[N,512] ----------------

__global__ void k_f2b_strided(const float* __restrict__ x, ushort* __restrict__ gh) {
    int i = blockIdx.x * blockDim.x + threadIdx.x;   // one per 4 elems
    if (i >= NNODES * 64) return;
    int v = i >> 6, c = (i & 63) * 4;
    float4 f = *(const float4*)(x + (size_t)v * 256 + c);
    union { bf16 h[4]; uint2 u; } o;
    o.h[0] = __float2bfloat16(f.x); o.h[1] = __float2bfloat16(f.y);
    o.h[2] = __float2bfloat16(f.z); o.h[3] = __float2bfloat16(f.w);
    *(uint2*)(gh + (size_t)v * 512 + 256 + c) = o.u;
}

// ---------------- degree histograms via LDS (no global atomics) ----------------

__global__ __launch_bounds__(256) void k_hist(const int* __restrict__ ei, ushort* __restrict__ partials) {
    __shared__ unsigned int h32[HBINS / 2];   // 100352 B LDS
    int b = blockIdx.x, row = blockIdx.y, t = threadIdx.x;
    for (int i = t; i < HBINS / 2; i += 256) h32[i] = 0;
    __syncthreads();
    const int chunk = NEDGES / HNB;  // 6250
    int beg = b * chunk, end = beg + chunk;
    const int* p = ei + (size_t)row * NEDGES;
    for (int e = beg + t; e < end; e += 256) {
        int id = p[e];
        atomicAdd(&h32[id >> 1], 1u << (16 * (id & 1)));
    }
    __syncthreads();
    unsigned int* o32 = (unsigned int*)(partials + ((size_t)row * HNB + b) * HBINS);
    for (int i = t; i < HBINS / 2; i += 256) o32[i] = h32[i];
}

// reduce partials: y=0 -> rsqrt_out table; y=1 -> in_cnt + per-256-node block_sums
__global__ __launch_bounds__(256) void k_hist_reduce(const ushort* __restrict__ partials,
                                                     float* __restrict__ rsqrt_out,
                                                     int* __restrict__ in_cnt,
                                                     int* __restrict__ block_sums) {
    __shared__ int sm[256];
    int row = blockIdx.y;
    int i = blockIdx.x * 256 + threadIdx.x;
    const ushort* p = partials + (size_t)row * HNB * HBINS + i;
    int s = 0;
#pragma unroll 4
    for (int b = 0; b < HNB; ++b) s += p[(size_t)b * HBINS];
    if (row == 0) {
        if (i < NNODES) rsqrt_out[i] = rsqrtf((float)s);
    } else {
        if (i < NNODES) in_cnt[i] = s;
        sm[threadIdx.x] = s;
        __syncthreads();
        for (int off = 128; off > 0; off >>= 1) {
            if (threadIdx.x < off) sm[threadIdx.x] += sm[threadIdx.x + off];
            __syncthreads();
        }
        if (threadIdx.x == 0) block_sums[blockIdx.x] = sm[0];
    }
}

// ---------------- scan ----------------

__global__ void k_scan_blocks(const int* __restrict__ block_sums, int* __restrict__ block_base, int nb) {
    __shared__ int s[256];
    int t = threadIdx.x;
    int v = (t < nb) ? block_sums[t] : 0;
    s[t] = v;
    __syncthreads();
    for (int off = 1; off < 256; off <<= 1) {
        int u = (t >= off) ? s[t - off] : 0;
        __syncthreads();
        s[t] += u;
        __syncthreads();
    }
    block_base[t] = s[t] - v;  // exclusive
}

__global__ void k_scan_final(const int* __restrict__ in_cnt, const int* __restrict__ block_base,
                             int* __restrict__ offsets, int* __restrict__ cursor) {
    __shared__ int s[256];
    int b = blockIdx.x, t = threadIdx.x;
    int i = b * 256 + t;
    int v = (i < NNODES) ? in_cnt[i] : 0;
    s[t] = v;
    __syncthreads();
    for (int off = 1; off < 256; off <<= 1) {
        int u = (t >= off) ? s[t - off] : 0;
        __syncthreads();
        s[t] += u;
        __syncthreads();
    }
    int excl = s[t] - v + block_base[b];
    if (i < NNODES) { offsets[i] = excl; cursor[i] = excl; }
    if (i == NNODES - 1) offsets[NNODES] = excl + v;
}

// counting-sort scatter: (src, out-norm) packed int2 per edge, bucketed by dst
__global__ void k_scatter(const int* __restrict__ ei, const float* __restrict__ rsqrt_out,
                          int* __restrict__ cursor, int2* __restrict__ edge_sw) {
    int e = blockIdx.x * blockDim.x + threadIdx.x;
    if (e < NEDGES) {
        int r = ei[e], c = ei[NEDGES + e];
        int p = atomicAdd(&cursor[c], 1);
        edge_sw[p] = make_int2(r, __float_as_int(rsqrt_out[r]));
    }
}

// ---------------- gather: G = in_norm * (S . H), column-split passes ----------------
// hsrc = right half of ghcat (pre-offset); rows stride 512 ushorts. Gdst = left half.
// 8 groups x 8 lanes per wave; group owns ONE node and the full 64-col slice alone:
// no cross-group reduce, no shuffles. Pass y covers cols [y*64, y*64+64).
// Per-pass unique footprint = 50000*128 B = 6.4 MB -> L2-friendly (R6-proven).
__global__ __launch_bounds__(256) void k_gather(const ushort* __restrict__ hsrc,
                                                const int* __restrict__ offsets,
                                                const int2* __restrict__ edge_sw,
                                                ushort* __restrict__ Gdst) {
    int lane = threadIdx.x & 63;
    int v = blockIdx.x * 32 + (threadIdx.x >> 6) * 8 + (lane >> 3);
    if (v >= NNODES) return;
    int sl = lane & 7;
    int col0 = blockIdx.y * 64;

    int beg = offsets[v], end = offsets[v + 1];
    float a0[8], a1[8];
#pragma unroll
    for (int c = 0; c < 8; ++c) { a0[c] = 0.f; a1[c] = 0.f; }

    const ushort* base = hsrc + col0 + sl * 8;
    int j = beg;
    for (; j + 2 <= end; j += 2) {
        int2 e0 = edge_sw[j];
        int2 e1 = edge_sw[j + 1];
        uint4 q0 = *(const uint4*)(base + (size_t)e0.x * 512);
        uint4 q1 = *(const uint4*)(base + (size_t)e1.x * 512);
        fma8(a0, __int_as_float(e0.y), q0);
        fma8(a1, __int_as_float(e1.y), q1);
    }
    if (j < end) {
        int2 e0 = edge_sw[j];
        uint4 q0 = *(const uint4*)(base + (size_t)e0.x * 512);
        fma8(a0, __int_as_float(e0.y), q0);
    }
    float sc = (end > beg) ? rsqrtf((float)(end - beg)) : 0.f;
    union { bf16 h[8]; uint4 u; } o;
#pragma unroll
    for (int c = 0; c < 8; ++c) o.h[c] = __float2bfloat16((a0[c] + a1[c]) * sc);
    *(uint4*)(Gdst + (size_t)v * 512 + col0 + sl * 8) = o.u;
}

// ---------------- MFMA GEMM: [G|H][N,512] @ stackedB[512,CC] + b, act ----------------
// 128x128 tile, BK=32, global_load_lds 16B staging, 4 waves 2x2, 16 MFMA/wave/k-step.
// ACT: 1 = relu -> bf16 at Out[v*OST + OOFF + col]; 2 = sigmoid -> fp32 at Out[v*OST + col].
template<int CC, int OST, int OOFF, int ACT>
__global__ __launch_bounds__(256) void k_gemm(const ushort* __restrict__ A,
                                              const bf16* __restrict__ Bt,
                                              const float* __restrict__ bias,
                                              void* __restrict__ Out) {
    __shared__ bf16 As[128 * 32];   // 8 KB
    __shared__ bf16 Bs[128 * 32];   // 8 KB
    int t = threadIdx.x;
    int wave = t >> 6, lane = t & 63;
    int r0 = blockIdx.x * 128;
    int n0 = blockIdx.y * 128;
    int wr = wave >> 1, wc = wave & 1;

    f4v acc[4][4];
#pragma unroll
    for (int i = 0; i < 4; ++i)
#pragma unroll
        for (int j = 0; j < 4; ++j) acc[i][j] = (f4v){0.f, 0.f, 0.f, 0.f};

    const char* Ab = (const char*)A;
    const char* Bb = (const char*)Bt;
    for (int k0 = 0; k0 < 512; k0 += 32) {
#pragma unroll
        for (int r = 0; r < 2; ++r) {
            int o = r * 4096 + wave * 1024 + lane * 16;  // byte offset in 8 KB tile
            int row = o >> 6, kb = o & 63;
            if (r0 + row < NNODES)
                gld_lds16(Ab + (size_t)(r0 + row) * 1024 + k0 * 2 + kb, (char*)As + o);
            gld_lds16(Bb + (size_t)(n0 + row) * 1024 + k0 * 2 + kb, (char*)Bs + o);
        }
        __syncthreads();
        int ml = lane & 15, kq = (lane >> 4) * 8;
        s8v a[4], b[4];
#pragma unroll
        for (int i = 0; i < 4; ++i)
            a[i] = *(const s8v*)&As[(wr * 64 + i * 16 + ml) * 32 + kq];
#pragma unroll
        for (int j = 0; j < 4; ++j)
            b[j] = *(const s8v*)&Bs[(wc * 64 + j * 16 + ml) * 32 + kq];
#pragma unroll
        for (int i = 0; i < 4; ++i)
#pragma unroll
            for (int j = 0; j < 4; ++j)
                acc[i][j] = __builtin_amdgcn_mfma_f32_16x16x32_bf16(a[i], b[j], acc[i][j], 0, 0, 0);
        __syncthreads();
    }
    // epilogue: C/D layout col=lane&15, row=(lane>>4)*4+reg; + bias, activation
    int ml = lane & 15, q4 = (lane >> 4) * 4;
#pragma unroll
    for (int i = 0; i < 4; ++i) {
#pragma unroll
        for (int rr = 0; rr < 4; ++rr) {
            int grow = r0 + wr * 64 + i * 16 + q4 + rr;
            if (grow < NNODES) {
#pragma unroll
                for (int j = 0; j < 4; ++j) {
                    int gcol = n0 + wc * 64 + j * 16 + ml;
                    float vv = acc[i][j][rr] + bias[gcol];
                    if (ACT == 1) {
                        ((ushort*)Out)[(size_t)grow * OST + OOFF + gcol] =
                            __bfloat16_as_ushort(__float2bfloat16(fmaxf(vv, 0.f)));
                    } else {
                        ((float*)Out)[(size_t)grow * OST + gcol] = 1.f / (1.f + expf(-vv));
                    }
                }
            }
        }
    }
}

// ---------------- launcher ----------------

extern "C" void kernel_launch(void* const* d_in, const int* in_sizes, int n_in,
                              void* d_out, int out_size, void* d_ws, size_t ws_size,
                              hipStream_t stream) {
    const float* x   = (const float*)d_in[0];
    const int*   ei  = (const int*)d_in[1];
    const float* w1  = (const float*)d_in[3];
    const float* lw1 = (const float*)d_in[4];
    const float* lb1 = (const float*)d_in[5];
    const float* w2  = (const float*)d_in[6];
    const float* lw2 = (const float*)d_in[7];
    const float* lb2 = (const float*)d_in[8];
    const float* w3  = (const float*)d_in[9];
    const float* lw3 = (const float*)d_in[10];
    const float* lb3 = (const float*)d_in[11];
    float* out = (float*)d_out;

    char* ws = (char*)d_ws;
    size_t off = 0;
    auto alloc = [&](size_t bytes) -> void* {
        void* p = ws + off;
        off += (bytes + 255) & ~(size_t)255;
        return p;
    };
    int*    in_cnt     = (int*)alloc((size_t)HBINS * 4);
    float*  rsqrt_out  = (float*)alloc((size_t)HBINS * 4);
    int*    offsets    = (int*)alloc((size_t)(NNODES + 1) * 4);
    int*    cursor     = (int*)alloc((size_t)NNODES * 4);
    int*    block_sums = (int*)alloc((size_t)256 * 4);
    int*    block_base = (int*)alloc((size_t)256 * 4);
    ushort* partials   = (ushort*)alloc((size_t)2 * HNB * HBINS * 2);   // 25.7 MB
    int2*   edge_sw    = (int2*)alloc((size_t)NEDGES * 8);              // 6.4 MB
    bf16*   wt1        = (bf16*)alloc((size_t)256 * 512 * 2);
    bf16*   wt2        = (bf16*)alloc((size_t)256 * 512 * 2);
    bf16*   wt3        = (bf16*)alloc((size_t)128 * 512 * 2);
    ushort* ghA        = (ushort*)alloc((size_t)NNODES * 512 * 2);      // 51.2 MB
    ushort* ghB        = (ushort*)alloc((size_t)NNODES * 512 * 2);      // 51.2 MB
    // ~136 MB total

    // weights: stack [[W],[LW]] along K and transpose -> [CC][512]
    k_packbt<<<512, 256, 0, stream>>>(w1, lw1, wt1, 256);
    k_packbt<<<512, 256, 0, stream>>>(w2, lw2, wt2, 256);
    k_packbt<<<256, 256, 0, stream>>>(w3, lw3, wt3, 128);
    // x -> bf16 into ghA right half
    k_f2b_strided<<<(NNODES * 64 + 255) / 256, 256, 0, stream>>>(x, ghA);

    // graph preprocessing
    k_hist<<<dim3(HNB, 2), 256, 0, stream>>>(ei, partials);
    k_hist_reduce<<<dim3(SCAN_NB, 2), 256, 0, stream>>>(partials, rsqrt_out, in_cnt, block_sums);
    k_scan_blocks<<<1, 256, 0, stream>>>(block_sums, block_base, SCAN_NB);
    k_scan_final<<<SCAN_NB, 256, 0, stream>>>(in_cnt, block_base, offsets, cursor);
    k_scatter<<<(NEDGES + 255) / 256, 256, 0, stream>>>(ei, rsqrt_out, cursor, edge_sw);

    dim3 ggrid((NNODES + 31) / 32, 4);   // 1563 x 4 column passes
    int gx = (NNODES + 127) / 128;       // 391

    // layer 1: G1 = S.xb -> ghA left; h1 = relu([G1|xb]@[[w1],[lw1]]+b1) -> ghB right
    k_gather<<<ggrid, 256, 0, stream>>>(ghA + 256, offsets, edge_sw, ghA);
    k_gemm<256, 512, 256, 1><<<dim3(gx, 2), 256, 0, stream>>>(ghA, wt1, lb1, ghB);
    // layer 2: G2 = S.h1 -> ghB left; h2 -> ghA right (ghA free after gemm1)
    k_gather<<<ggrid, 256, 0, stream>>>(ghB + 256, offsets, edge_sw, ghB);
    k_gemm<256, 512, 256, 1><<<dim3(gx, 2), 256, 0, stream>>>(ghB, wt2, lb2, ghA);
    // layer 3: G3 = S.h2 -> ghA left; out = sigmoid([G3|h2]@[[w3],[lw3]]+b3) fp32
    k_gather<<<ggrid, 256, 0, stream>>>(ghA + 256, offsets, edge_sw, ghA);
    k_gemm<128, 128, 0, 2><<<dim3(gx, 1), 256, 0, stream>>>(ghA, wt3, lb3, out);
}